// Round 5
// baseline (63.622 us; speedup 1.0000x reference)
//
#include <hip/hip_runtime.h>
#include <stdint.h>

typedef unsigned long long u64;
typedef unsigned int u32;

#define BATCH 32
#define H 512
#define W 512
#define WPR 8                     // u64 words per row
#define WORDS_IMG (H * WPR)       // 4096
#define NPIX (H * W)

#define NSTRIP 8
#define OWN 64

// phase 0 geometry (24 pairs)
#define HALO0 48
#define RL0 160                   // OWN + 2*HALO0
#define PAIRS0 24
#define THR0 640                  // RL0*8/2

// phase 1/2 geometry (16 pairs)
#define HALO1 32
#define RL1 128
#define PAIRS1 16
#define THR1 512

#define WP 9                      // padded LDS row stride (u64)
#define ERL 68                    // OWN + 2+2 rows for double dilation

// ---------------- pack: y(int32 0/1) -> bitboards via 64-bit ballot ----------
__global__ __launch_bounds__(256) void pack_kernel(const int* __restrict__ y,
                                                   u64* __restrict__ words) {
    int gtid = blockIdx.x * blockDim.x + threadIdx.x;
    int lane = gtid & 63;
    int wave = gtid >> 6;
    int nwaves = (gridDim.x * blockDim.x) >> 6;
    #pragma unroll 8
    for (int w = wave; w < BATCH * WORDS_IMG; w += nwaves) {
        int v = y[(size_t)w * 64 + lane];
        u64 m = __ballot(v != 0);
        if (lane == 0) words[w] = m;
    }
}

// ---------------- bit-sliced Zhang-Suen sub-iteration helpers ----------------
__device__ __forceinline__ void fulladd(u64 a, u64 b, u64 c, u64& s, u64& cy) {
    u64 t = a ^ b;
    s = t ^ c;
    cy = (a & b) | (t & c);
}

// strip version: RLp rows, stride WP, 2 rows per thread
template<bool FIRST, int RLp>
__device__ __forceinline__ u64 subiter2(const u64* __restrict__ src,
                                        u64* __restrict__ dst,
                                        int rg, int wc) {
    const int r = 2 * rg;
    u64 C[4], L[4], R[4];
    #pragma unroll
    for (int i = 0; i < 4; ++i) {
        int rr = r - 1 + i;
        bool v = (rr >= 0) && (rr < RLp);
        const u64* row = src + rr * WP;
        C[i] = v ? row[wc] : 0ull;
        L[i] = (v && wc > 0) ? row[wc - 1] : 0ull;
        R[i] = (v && wc < 7) ? row[wc + 1] : 0ull;
    }
    u64 Wst[4], Est[4];
    #pragma unroll
    for (int i = 0; i < 4; ++i) {
        Wst[i] = (C[i] << 1) | (L[i] >> 63);
        Est[i] = (C[i] >> 1) | (R[i] << 63);
    }
    u64 diff = 0;
    #pragma unroll
    for (int k = 0; k < 2; ++k) {
        u64 P2 = C[k],     P9 = Wst[k],     P3 = Est[k];
        u64 cC = C[k + 1], P8 = Wst[k + 1], P4 = Est[k + 1];
        u64 P6 = C[k + 2], P7 = Wst[k + 2], P5 = Est[k + 2];

        u64 s1, c1, s2, c2, s3, c3, ts, tc, us, uc;
        fulladd(P2, P3, P4, s1, c1);
        fulladd(P5, P6, P7, s2, c2);
        s3 = P8 ^ P9; c3 = P8 & P9;
        fulladd(s1, s2, s3, ts, tc);
        fulladd(c1, c2, c3, us, uc);
        u64 vs = us ^ tc, vc = us & tc;
        u64 w4 = uc ^ vc, w8 = uc & vc;
        u64 condB = (vs | w4 | w8) & ~(w8 | (w4 & vs & ts));

        u64 seen, multi, t;
        t = ~P2 & P3; seen = t;  multi = 0;
        t = ~P3 & P4; multi |= seen & t; seen |= t;
        t = ~P4 & P5; multi |= seen & t; seen |= t;
        t = ~P5 & P6; multi |= seen & t; seen |= t;
        t = ~P6 & P7; multi |= seen & t; seen |= t;
        t = ~P7 & P8; multi |= seen & t; seen |= t;
        t = ~P8 & P9; multi |= seen & t; seen |= t;
        t = ~P9 & P2; multi |= seen & t; seen |= t;
        u64 ex1 = seen & ~multi;

        u64 cond = FIRST ? (~(P2 & P4 & P6) & ~(P4 & P6 & P8))
                         : (~(P2 & P4 & P8) & ~(P2 & P6 & P8));

        u64 rem = cC & condB & ex1 & cond;
        u64 nw = cC & ~rem;
        dst[(r + k) * WP + wc] = nw;
        diff |= nw ^ cC;
    }
    return diff;
}

// --------------- strip dispatch: halo-redundant local iteration -------------
template<int RLp, int HALOp, int PAIRSp, int THRp>
__global__ __launch_bounds__(THRp)
void strip_iter_t(const u64* __restrict__ gsrc, u64* __restrict__ gdst,
                  int* __restrict__ flags, int phase) {
    if (phase > 0 && flags[phase - 1] == 0) return;   // already converged

    __shared__ u64 A[RLp * WP];
    __shared__ u64 Bf[RLp * WP];
    __shared__ int s_any[2];

    const int tid = threadIdx.x;
    const int blk = blockIdx.x;
    const int b = blk >> 3;
    const int s = blk & 7;
    const int row0 = s * OWN;
    const int lane = tid & 63;
    const u64* src = gsrc + (size_t)b * WORDS_IMG;
    u64* dst = gdst + (size_t)b * WORDS_IMG;

    #pragma unroll
    for (int i = 0; i < 2; ++i) {
        int t = tid + i * THRp;
        int lrow = t >> 3, c = t & 7;
        int grow = row0 - HALOp + lrow;
        u64 v = 0;
        if (grow >= 0 && grow < H) v = src[grow * WPR + c];
        A[lrow * WP + c] = v;
    }
    if (tid < 2) s_any[tid] = 0;
    __syncthreads();

    const int rg = tid >> 3;
    const int wc = tid & 7;
    const int rgLo = HALOp / 2;
    const int rgHi = rgLo + OWN / 2;
    u64 lastown = 0;
    for (int pr = 0; pr < PAIRSp; ++pr) {
        u64 d1 = subiter2<true, RLp>(A, Bf, rg, wc);
        __syncthreads();
        u64 d2 = subiter2<false, RLp>(Bf, A, rg, wc);
        u64 d = d1 | d2;
        lastown = (rg >= rgLo && rg < rgHi) ? d : 0;
        int p = pr & 1;
        u64 bal = __ballot(d != 0);
        if (lane == 0 && bal) atomicOr(&s_any[p], 1);
        __syncthreads();                  // A visible + s_any settled
        int any = s_any[p];
        if (tid == 0) s_any[p ^ 1] = 0;
        if (!any) break;                  // local fixpoint -> rest is identity
    }

    if (rg >= rgLo && rg < rgHi) {
        int r = 2 * rg;
        dst[(row0 + r - HALOp) * WPR + wc]     = A[r * WP + wc];
        dst[(row0 + r - HALOp + 1) * WPR + wc] = A[(r + 1) * WP + wc];
    }
    u64 bal = __ballot(lastown != 0);
    if (lane == 0 && bal) atomicOr(&flags[phase], 1);
}

// full-image sub-iteration for the fallback kernel (stride WPR, 8 rows/thread)
template<bool FIRST>
__device__ __forceinline__ void compute_sub_full(const u64* img, int wc, int r0,
                                                 u64 nw[8], u64& diff) {
    u64 C[10], L[10], R[10];
    #pragma unroll
    for (int i = 0; i < 10; ++i) {
        int rr = r0 - 1 + i;
        bool valid = (rr >= 0) && (rr < H);
        C[i] = valid ? img[rr * WPR + wc] : 0ull;
        L[i] = (valid && wc > 0) ? img[rr * WPR + wc - 1] : 0ull;
        R[i] = (valid && wc < WPR - 1) ? img[rr * WPR + wc + 1] : 0ull;
    }
    #pragma unroll
    for (int k = 0; k < 8; ++k) {
        u64 P2 = C[k];
        u64 P9 = (C[k]   << 1) | (L[k]   >> 63);
        u64 P3 = (C[k]   >> 1) | (R[k]   << 63);
        u64 cC = C[k+1];
        u64 P8 = (C[k+1] << 1) | (L[k+1] >> 63);
        u64 P4 = (C[k+1] >> 1) | (R[k+1] << 63);
        u64 P6 = C[k+2];
        u64 P7 = (C[k+2] << 1) | (L[k+2] >> 63);
        u64 P5 = (C[k+2] >> 1) | (R[k+2] << 63);

        u64 s1, c1, s2, c2, s3, c3, ts, tc, us, uc;
        fulladd(P2, P3, P4, s1, c1);
        fulladd(P5, P6, P7, s2, c2);
        s3 = P8 ^ P9; c3 = P8 & P9;
        fulladd(s1, s2, s3, ts, tc);
        fulladd(c1, c2, c3, us, uc);
        u64 vs = us ^ tc, vc = us & tc;
        u64 w4 = uc ^ vc, w8 = uc & vc;
        u64 condB = (vs | w4 | w8) & ~(w8 | (w4 & vs & ts));

        u64 seen, multi, t;
        t = ~P2 & P3; seen = t;  multi = 0;
        t = ~P3 & P4; multi |= seen & t; seen |= t;
        t = ~P4 & P5; multi |= seen & t; seen |= t;
        t = ~P5 & P6; multi |= seen & t; seen |= t;
        t = ~P6 & P7; multi |= seen & t; seen |= t;
        t = ~P7 & P8; multi |= seen & t; seen |= t;
        t = ~P8 & P9; multi |= seen & t; seen |= t;
        t = ~P9 & P2; multi |= seen & t; seen |= t;
        u64 ex1 = seen & ~multi;

        u64 cond = FIRST ? (~(P2 & P4 & P6) & ~(P4 & P6 & P8))
                         : (~(P2 & P4 & P8) & ~(P2 & P6 & P8));

        u64 rem = cC & condB & ex1 & cond;
        nw[k] = cC & ~rem;
        diff |= nw[k] ^ cC;
    }
}

// --------------- fallback: exact fixpoint if 56 pairs weren't enough --------
__global__ __launch_bounds__(512)
void fallback_kernel(u64* __restrict__ gimg0, const int* __restrict__ flags) {
    if (flags[2] == 0) return;

    __shared__ u64 img[WORDS_IMG];        // 32 KB
    __shared__ int s_changed;
    const int b = blockIdx.x;
    const int tid = threadIdx.x;
    const int wc = tid & 7;
    const int r0 = (tid >> 3) * 8;
    u64* gimg = gimg0 + (size_t)b * WORDS_IMG;

    #pragma unroll
    for (int k = 0; k < 8; ++k)
        img[(r0 + k) * WPR + wc] = gimg[(r0 + k) * WPR + wc];
    if (tid == 0) s_changed = 0;
    __syncthreads();

    bool changed = true;
    for (int it = 0; it < 4096 && changed; ++it) {
        u64 diff = 0;
        u64 nw[8];
        compute_sub_full<true>(img, wc, r0, nw, diff);
        __syncthreads();
        #pragma unroll
        for (int k = 0; k < 8; ++k) img[(r0 + k) * WPR + wc] = nw[k];
        __syncthreads();
        compute_sub_full<false>(img, wc, r0, nw, diff);
        __syncthreads();
        #pragma unroll
        for (int k = 0; k < 8; ++k) img[(r0 + k) * WPR + wc] = nw[k];
        if (diff) atomicOr(&s_changed, 1);
        __syncthreads();
        changed = (s_changed != 0);
        __syncthreads();
        if (tid == 0) s_changed = 0;
    }

    #pragma unroll
    for (int k = 0; k < 8; ++k)
        gimg[(r0 + k) * WPR + wc] = img[(r0 + k) * WPR + wc];
}

// --------------- tail: dilate x2 + gt popcount + x-intersection -------------
__global__ __launch_bounds__(512)
void tail_kernel(const u64* __restrict__ gA, const u64* __restrict__ gB,
                 const int* __restrict__ flags, const float* __restrict__ x,
                 float* __restrict__ partial, int* __restrict__ partial_gt) {
    int f0 = flags[0], f1 = flags[1];
    // phase0 -> gB, phase1 -> gA, phase2 -> gB, fallback in-place gB
    const u64* cur = f1 ? gB : (f0 ? gA : gB);

    __shared__ u64 D[ERL * WP];
    __shared__ u64 E[ERL * WP];
    __shared__ float s_red[8];
    __shared__ int s_pc[8];

    const int tid = threadIdx.x;
    const int blk = blockIdx.x;
    const int b = blk >> 3;
    const int s = blk & 7;
    const int row0 = s * OWN;
    const int lane = tid & 63;
    const int wv = tid >> 6;
    const u64* src = cur + (size_t)b * WORDS_IMG;
    const float* xb = x + (size_t)b * NPIX;

    for (int t = tid; t < ERL * 8; t += 512) {
        int lrow = t >> 3, c = t & 7;
        int grow = row0 - 2 + lrow;
        u64 v = 0;
        if (grow >= 0 && grow < H) v = src[grow * WPR + c];
        D[lrow * WP + c] = v;
    }
    __syncthreads();

    // dilate pass 1: D -> E
    for (int t = tid; t < ERL * 8; t += 512) {
        int l = t >> 3, c = t & 7;
        int grow = row0 - 2 + l;
        u64 v = 0;
        if (grow >= 0 && grow < H) {
            u64 cc = D[l * WP + c];
            u64 up = (l > 0)       ? D[(l - 1) * WP + c] : 0ull;
            u64 dn = (l < ERL - 1) ? D[(l + 1) * WP + c] : 0ull;
            u64 lw = (c > 0) ? D[l * WP + c - 1] : 0ull;
            u64 rw = (c < 7) ? D[l * WP + c + 1] : 0ull;
            v = cc | up | dn | ((cc << 1) | (lw >> 63)) | ((cc >> 1) | (rw << 63));
        }
        E[l * WP + c] = v;
    }
    __syncthreads();

    // dilate pass 2: owned rows only (LDS rows 2..65), one word per thread
    const int l = 2 + (tid >> 3);
    const int c = tid & 7;
    u64 v;
    {
        u64 cc = E[l * WP + c];
        u64 up = E[(l - 1) * WP + c];
        u64 dn = E[(l + 1) * WP + c];
        u64 lw = (c > 0) ? E[l * WP + c - 1] : 0ull;
        u64 rw = (c < 7) ? E[l * WP + c + 1] : 0ull;
        v = cc | up | dn | ((cc << 1) | (lw >> 63)) | ((cc >> 1) | (rw << 63));
    }
    int pc = __popcll(v);
    for (int off = 32; off >= 1; off >>= 1) pc += __shfl_down(pc, off, 64);
    if (lane == 0) s_pc[wv] = pc;
    __syncthreads();          // E fully consumed by all threads
    D[l * WP + c] = v;        // store dilated board into D
    __syncthreads();

    // intersection: thread owns column tid; 4 independent accumulators
    float s0 = 0.0f, s1 = 0.0f, s2 = 0.0f, s3 = 0.0f;
    #pragma unroll 4
    for (int i = 0; i < 64; i += 4) {
        u64 w0 = D[(2 + i) * WP + wv];
        u64 w1 = D[(3 + i) * WP + wv];
        u64 w2 = D[(4 + i) * WP + wv];
        u64 w3 = D[(5 + i) * WP + wv];
        const float* xr = xb + (size_t)(row0 + i) * W + tid;
        s0 = fmaf((float)((w0 >> lane) & 1ull), xr[0],     s0);
        s1 = fmaf((float)((w1 >> lane) & 1ull), xr[W],     s1);
        s2 = fmaf((float)((w2 >> lane) & 1ull), xr[2 * W], s2);
        s3 = fmaf((float)((w3 >> lane) & 1ull), xr[3 * W], s3);
    }
    float sum = (s0 + s1) + (s2 + s3);
    for (int off = 32; off >= 1; off >>= 1) sum += __shfl_down(sum, off, 64);
    if (lane == 0) s_red[wv] = sum;
    __syncthreads();
    if (tid == 0) {
        float fs = 0.0f;
        int is = 0;
        #pragma unroll
        for (int k = 0; k < 8; ++k) { fs += s_red[k]; is += s_pc[k]; }
        partial[blk] = fs;
        partial_gt[blk] = is;
    }
}

// --------------- final: recall per image, mean, negate; reset flags ---------
__global__ __launch_bounds__(64)
void final_kernel(const float* __restrict__ partial,
                  const int* __restrict__ partial_gt,
                  int* __restrict__ flags,
                  float* __restrict__ out) {
    __shared__ float rec[32];
    int t = threadIdx.x;
    if (t < 3) flags[t] = 0;     // reset for the next call
    if (t < 32) {
        float inter = 0.0f;
        int g = 0;
        #pragma unroll
        for (int j = 0; j < 8; ++j) {
            inter += partial[t * 8 + j];
            g += partial_gt[t * 8 + j];
        }
        rec[t] = (inter + 1.0f) / ((float)g + 1.0f);
    }
    __syncthreads();
    if (t == 0) {
        float s = 0.0f;
        for (int i = 0; i < 32; ++i) s += rec[i];
        out[0] = -(s / 32.0f);
    }
}

extern "C" void kernel_launch(void* const* d_in, const int* in_sizes, int n_in,
                              void* d_out, int out_size, void* d_ws, size_t ws_size,
                              hipStream_t stream) {
    const float* x = (const float*)d_in[0];
    const int*   y = (const int*)d_in[1];
    float* out = (float*)d_out;

    char* ws = (char*)d_ws;
    u64* gA = (u64*)ws;
    u64* gB = (u64*)(ws + (size_t)BATCH * WORDS_IMG * 8);
    int* flags = (int*)(ws + 2 * (size_t)BATCH * WORDS_IMG * 8);
    float* partial = (float*)(flags + 4);
    int* partial_gt = (int*)(partial + BATCH * NSTRIP);

    pack_kernel<<<512, 256, 0, stream>>>(y, gA);
    strip_iter_t<RL0, HALO0, PAIRS0, THR0>
        <<<BATCH * NSTRIP, THR0, 0, stream>>>(gA, gB, flags, 0);
    strip_iter_t<RL1, HALO1, PAIRS1, THR1>
        <<<BATCH * NSTRIP, THR1, 0, stream>>>(gB, gA, flags, 1);
    strip_iter_t<RL1, HALO1, PAIRS1, THR1>
        <<<BATCH * NSTRIP, THR1, 0, stream>>>(gA, gB, flags, 2);
    fallback_kernel<<<BATCH, 512, 0, stream>>>(gB, flags);
    tail_kernel<<<BATCH * NSTRIP, 512, 0, stream>>>(gA, gB, flags, x,
                                                    partial, partial_gt);
    final_kernel<<<1, 64, 0, stream>>>(partial, partial_gt, flags, out);
}